// Round 1
// 5513.071 us; speedup vs baseline: 1.7873x; 1.7873x over previous
//
#include <hip/hip_runtime.h>

typedef short short8 __attribute__((ext_vector_type(8)));
typedef float floatx4 __attribute__((ext_vector_type(4)));
typedef unsigned short u16;
typedef unsigned u32;
typedef unsigned long long u64;

#define MFMA16 __builtin_amdgcn_mfma_f32_16x16x32_bf16

#define B_  64
#define T_  512
#define I_  256
#define H_  1024
#define CNT_STRIDE 64    // uints; one counter per 256B
#define XS_STRIDE 272    // u16; 544B = 8 banks mod 32 -> 2-way max on A-reads
#define HS_STRIDE 1040   // u16; 2080B = 8 banks mod 32

// round-to-nearest-even fp32 -> bf16 (as u16)
__device__ __forceinline__ u16 rne_bf(float f) {
    union { float f; u32 i; } v; v.f = f;
    return (u16)((v.i + 0x7fffu + ((v.i >> 16) & 1u)) >> 16);
}
// split fp32 into bf16 hi + bf16 lo (hi RNE, lo = RNE(f - hi)); |f-hi-lo| <= 2^-16 |f|
__device__ __forceinline__ void split_bf(float f, u16& hi, u16& lo) {
    u16 h = rne_bf(f);
    union { u32 i; float f; } hf; hf.i = ((u32)h) << 16;
    hi = h;
    lo = rne_bf(f - hf.f);
}
__device__ __forceinline__ void split4(float4 v, u64& hi64, u64& lo64) {
    u16 h0,l0,h1,l1,h2,l2,h3,l3;
    split_bf(v.x,h0,l0); split_bf(v.y,h1,l1);
    split_bf(v.z,h2,l2); split_bf(v.w,h3,l3);
    hi64 = (u64)h0 | ((u64)h1 << 16) | ((u64)h2 << 32) | ((u64)h3 << 48);
    lo64 = (u64)l0 | ((u64)l1 << 16) | ((u64)l2 << 32) | ((u64)l3 << 48);
}

// grid = 256 blocks: blockIdx = cb*16 + g
//   g  (0..15): batch group, batches 4g..4g+3  (stride-16 peers -> same XCD under %8)
//   cb (0..15): column block, cols 64cb..64cb+63
// block = 256 threads = 4 waves; wave w owns cols 64cb+16w .. +15
//
// Cross-block h exchange is done ENTIRELY through device-coherent (sc0 sc1)
// instructions: sc1 publish stores + agent-scope atomic loads for h.  No
// cached line ever carries h, so NO acquire fence (buffer_inv) and NO release
// writeback are needed -- the per-step L2 nuke of the previous version (the
// source of 17 GB of HBM refill traffic) is gone.
__global__ __launch_bounds__(256, 1) void leaky_rnn(
    const float* __restrict__ x, const float* __restrict__ eps,
    const float* __restrict__ in_w, const float* __restrict__ in_b,
    const float* __restrict__ W, const float* __restrict__ taus,
    float* __restrict__ out, float* __restrict__ hbf, unsigned* __restrict__ cnt)
{
    __shared__ float Wl[128 * 68];           // init-only W staging
    __shared__ u16 xs_hi[4 * XS_STRIDE];
    __shared__ u16 xs_lo[4 * XS_STRIDE];
    __shared__ u16 hs_hi[4 * HS_STRIDE];
    __shared__ u16 hs_lo[4 * HS_STRIDE];

    const int tid  = threadIdx.x;
    const int wave = tid >> 6;
    const int lane = tid & 63;
    const int n    = lane & 15;
    const int quad = lane >> 4;
    const int g    = blockIdx.x & 15;
    const int cb   = blockIdx.x >> 4;
    const int jme  = cb * 64 + wave * 16 + n;   // my output column

    // ---- init: W column-slice -> split-bf16 register B-fragments ----
    // B-frag layout (16x16x32): n = lane&15, k = quad*8 + i
    short8 whi[32], wlo[32];
    #pragma unroll 1
    for (int ph = 0; ph < 8; ++ph) {            // 8 phases x 128 rows
        #pragma unroll
        for (int ii = 0; ii < 8; ++ii) {        // stage 128x64 fp32 tile
            int f4i = ii * 256 + tid;           // 2048 float4
            int row = f4i >> 4, c4 = (f4i & 15) * 4;
            *(float4*)(Wl + row * 68 + c4) =
                *(const float4*)(W + (size_t)(ph * 128 + row) * H_ + cb * 64 + c4);
        }
        __syncthreads();
        #pragma unroll
        for (int ckl = 0; ckl < 4; ++ckl) {     // K-chunks of 32 within phase
            short8 fh, fl;
            #pragma unroll
            for (int i = 0; i < 8; ++i) {
                float v = Wl[(ckl * 32 + quad * 8 + i) * 68 + wave * 16 + n];
                u16 h, l; split_bf(v, h, l);
                fh[i] = (short)h; fl[i] = (short)l;
            }
            whi[ph * 4 + ckl] = fh;
            wlo[ph * 4 + ckl] = fl;
        }
        __syncthreads();
    }

    // in_w fragments: B[k][col] = in_w[col][k] -> 8 consecutive fp32 per chunk
    short8 iwhi[8], iwlo[8];
    #pragma unroll
    for (int ck = 0; ck < 8; ++ck) {
        float4 a = *(const float4*)(in_w + (size_t)jme * I_ + ck * 32 + quad * 8);
        float4 b = *(const float4*)(in_w + (size_t)jme * I_ + ck * 32 + quad * 8 + 4);
        short8 fh, fl;
        float vv[8] = {a.x, a.y, a.z, a.w, b.x, b.y, b.z, b.w};
        #pragma unroll
        for (int i = 0; i < 8; ++i) {
            u16 h, l; split_bf(vv[i], h, l);
            fh[i] = (short)h; fl[i] = (short)l;
        }
        iwhi[ck] = fh; iwlo[ck] = fl;
    }

    // per-column params (alpha time-invariant)
    float tv = taus[jme];
    float sg = 1.0f / (1.0f + __expf(-tv));
    float al = 10.0f / (sg * 90.0f + 10.0f);   // DT / (sigmoid(taus)*range + min)
    float om = 1.0f - al;
    float bj = in_b[jme];
    float hm[4] = {0.f, 0.f, 0.f, 0.f};        // fp32 master h (quad-0 lanes)

    unsigned* myc = cnt + g * CNT_STRIDE;

    #pragma unroll 1
    for (int t = 0; t < T_; ++t) {
        // ---- off-critical-path: eps prefetch + x_t staging (split-bf16) ----
        float epr[4];
        if (quad == 0) {
            #pragma unroll
            for (int r = 0; r < 4; ++r)
                epr[r] = eps[((g * 4 + r) * T_ + t) * H_ + jme];
        }
        {
            int b = tid >> 6, c = (tid & 63) * 4;    // 256 float4 = [4][256]
            float4 xv = *(const float4*)(x + ((g * 4 + b) * T_ + t) * I_ + c);
            u64 hi64, lo64; split4(xv, hi64, lo64);
            *(u64*)(xs_hi + b * XS_STRIDE + c) = hi64;
            *(u64*)(xs_lo + b * XS_STRIDE + c) = lo64;
        }
        __syncthreads();                                        // S0: xs ready

        // ---- wait for h_t publication from all 16 peers of this group ----
        // No acquire fence: h is read below with agent-scope (sc0 sc1) loads
        // that bypass L1/L2, so there are no stale cached lines to kill.
        if (tid == 0 && t > 0) {
            unsigned tgt = 16u * (unsigned)t;
            while (__hip_atomic_load(myc, __ATOMIC_RELAXED, __HIP_MEMORY_SCOPE_AGENT) < tgt)
                __builtin_amdgcn_s_sleep(1);
        }
        __syncthreads();                                        // S1: h published

        // ---- issue coherent h_t loads (8 x dwordx2, device coherence point);
        //      their ~900cy latency hides under the x-projection MFMAs below ----
        u64 hv[8];
        {
            u64* src8 = (u64*)(hbf + (size_t)((t & 1) * 16 + g) * 4096);
            #pragma unroll
            for (int ii = 0; ii < 8; ++ii)
                hv[ii] = __hip_atomic_load(src8 + ii * 256 + tid,
                                           __ATOMIC_RELAXED, __HIP_MEMORY_SCOPE_AGENT);
        }

        // ---- x @ in_w^T while h loads are in flight (24 MFMAs) ----
        floatx4 acc[8];
        #pragma unroll
        for (int a8 = 0; a8 < 8; ++a8) { floatx4 z = {0.f,0.f,0.f,0.f}; acc[a8] = z; }
        {
            const u16* xh = xs_hi + (n & 3) * XS_STRIDE + quad * 8;
            const u16* xl = xs_lo + (n & 3) * XS_STRIDE + quad * 8;
            #pragma unroll
            for (int ck = 0; ck < 8; ++ck) {
                short8 ah  = *(const short8*)(xh + ck * 32);
                short8 al8 = *(const short8*)(xl + ck * 32);
                acc[ck] = MFMA16(ah, iwhi[ck], acc[ck], 0, 0, 0);
                acc[ck] = MFMA16(ah, iwlo[ck], acc[ck], 0, 0, 0);
                acc[ck] = MFMA16(al8, iwhi[ck], acc[ck], 0, 0, 0);
            }
        }

        // ---- consume h loads: split-bf16 -> LDS ----
        {
            #pragma unroll
            for (int ii = 0; ii < 8; ++ii) {
                int idx = ii * 256 + tid;              // 2048 u64 = [4][512]
                int b = idx >> 9, c = (idx & 511) * 2;
                float f0 = __uint_as_float((u32)hv[ii]);
                float f1 = __uint_as_float((u32)(hv[ii] >> 32));
                u16 h0, l0, h1, l1;
                split_bf(f0, h0, l0); split_bf(f1, h1, l1);
                *(u32*)(hs_hi + b * HS_STRIDE + c) = (u32)h0 | ((u32)h1 << 16);
                *(u32*)(hs_lo + b * HS_STRIDE + c) = (u32)l0 | ((u32)l1 << 16);
            }
        }
        __syncthreads();                                        // S2: hs ready

        // ---- h @ W: 32 K-chunks x 3 split terms = 96 MFMAs ----
        {
            const u16* hh = hs_hi + (n & 3) * HS_STRIDE + quad * 8;
            const u16* hl = hs_lo + (n & 3) * HS_STRIDE + quad * 8;
            #pragma unroll
            for (int ck = 0; ck < 32; ++ck) {
                short8 ah  = *(const short8*)(hh + ck * 32);
                short8 al8 = *(const short8*)(hl + ck * 32);
                acc[ck & 7] = MFMA16(ah, whi[ck], acc[ck & 7], 0, 0, 0);
                acc[ck & 7] = MFMA16(ah, wlo[ck], acc[ck & 7], 0, 0, 0);
                acc[ck & 7] = MFMA16(al8, whi[ck], acc[ck & 7], 0, 0, 0);
            }
        }

        // ---- epilogue: C/D row = quad*4+reg -> quad 0 holds batches 0..3 ----
        if (quad == 0) {
            float* dst = hbf + (size_t)(((t + 1) & 1) * 16 + g) * 4096;
            #pragma unroll
            for (int r = 0; r < 4; ++r) {
                float pre = acc[0][r] + acc[1][r] + acc[2][r] + acc[3][r]
                          + acc[4][r] + acc[5][r] + acc[6][r] + acc[7][r]
                          + bj + 0.1f * epr[r];
                float ex = __expf(2.0f * pre);                 // tanh = 1 - 2/(e^2x+1)
                float th = 1.0f - 2.0f / (ex + 1.0f);
                hm[r] = om * hm[r] + al * th;
                out[((g * 4 + r) * T_ + t) * H_ + jme] = hm[r];
                // publish via sc1 store (bypasses L2 -> visible at coherence point)
                __hip_atomic_store((u32*)(dst + r * H_ + jme), __float_as_uint(hm[r]),
                                   __ATOMIC_RELAXED, __HIP_MEMORY_SCOPE_AGENT);
            }
        }
        __syncthreads();   // S3: barrier drains every wave's vmcnt -> all sc1
                           // publish stores are ack'd at the coherence point
                           // before wave 0 issues the counter bump below.
        if (tid == 0)
            __hip_atomic_fetch_add(myc, 1u, __ATOMIC_RELAXED, __HIP_MEMORY_SCOPE_AGENT);
    }
}

extern "C" void kernel_launch(void* const* d_in, const int* in_sizes, int n_in,
                              void* d_out, int out_size, void* d_ws, size_t ws_size,
                              hipStream_t stream) {
    const float* x    = (const float*)d_in[0];
    const float* eps  = (const float*)d_in[1];
    const float* in_w = (const float*)d_in[2];
    const float* in_b = (const float*)d_in[3];
    const float* W    = (const float*)d_in[4];
    const float* taus = (const float*)d_in[5];
    float* out = (float*)d_out;

    unsigned* cnt = (unsigned*)d_ws;                   // 16 counters @ 256B stride
    float* hbf = (float*)((char*)d_ws + 4096);         // [parity][16 groups][4][1024] fp32

    // zero counters + parity-0 h (h0 = 0); parity-1 is fully written before read
    hipMemsetAsync(d_ws, 0, 4096 + 16 * 4096 * sizeof(float), stream);

    leaky_rnn<<<dim3(256), dim3(256), 0, stream>>>(x, eps, in_w, in_b, W, taus,
                                                   out, hbf, cnt);
}

// Round 2
// 2526.222 us; speedup vs baseline: 3.9005x; 2.1823x over previous
//
#include <hip/hip_runtime.h>

typedef short short8 __attribute__((ext_vector_type(8)));
typedef float floatx4 __attribute__((ext_vector_type(4)));
typedef unsigned short u16;
typedef unsigned u32;
typedef unsigned long long u64;

#define MFMA16 __builtin_amdgcn_mfma_f32_16x16x32_bf16

#define B_  64
#define T_  512
#define I_  256
#define H_  1024
#define CNT_STRIDE 64    // uints; one counter per 256B
#define XS_STRIDE 272    // u16; 544B = 8 banks mod 32 -> 2-way max on A-reads
#define HS_STRIDE 1040   // u16; 2080B = 8 banks mod 32

// round-to-nearest-even fp32 -> bf16 (as u16)
__device__ __forceinline__ u16 rne_bf(float f) {
    union { float f; u32 i; } v; v.f = f;
    return (u16)((v.i + 0x7fffu + ((v.i >> 16) & 1u)) >> 16);
}
// split fp32 into bf16 hi + bf16 lo (hi RNE, lo = RNE(f - hi)); |f-hi-lo| <= 2^-16 |f|
__device__ __forceinline__ void split_bf(float f, u16& hi, u16& lo) {
    u16 h = rne_bf(f);
    union { u32 i; float f; } hf; hf.i = ((u32)h) << 16;
    hi = h;
    lo = rne_bf(f - hf.f);
}
__device__ __forceinline__ void split4(float4 v, u64& hi64, u64& lo64) {
    u16 h0,l0,h1,l1,h2,l2,h3,l3;
    split_bf(v.x,h0,l0); split_bf(v.y,h1,l1);
    split_bf(v.z,h2,l2); split_bf(v.w,h3,l3);
    hi64 = (u64)h0 | ((u64)h1 << 16) | ((u64)h2 << 32) | ((u64)h3 << 48);
    lo64 = (u64)l0 | ((u64)l1 << 16) | ((u64)l2 << 32) | ((u64)l3 << 48);
}

// grid = 256 blocks: blockIdx = cb*16 + g
//   g  (0..15): batch group, batches 4g..4g+3  (stride-16 peers -> same XCD under %8)
//   cb (0..15): column block, cols 64cb..64cb+63
// block = 256 threads = 4 waves; wave w owns cols 64cb+16w .. +15
//
// W fragments MUST live in registers: the init loop below is FULLY unrolled so
// every whi/wlo index is a compile-time constant (runtime-indexed ext_vector
// arrays are allocated in scratch -> 131 KB/block/step of refill traffic was
// the entire 17 GB FETCH_SIZE of the previous version).
__global__ __launch_bounds__(256, 1) void leaky_rnn(
    const float* __restrict__ x, const float* __restrict__ eps,
    const float* __restrict__ in_w, const float* __restrict__ in_b,
    const float* __restrict__ W, const float* __restrict__ taus,
    float* __restrict__ out, float* __restrict__ hbf, unsigned* __restrict__ cnt)
{
    __shared__ float Wl[128 * 68];           // init-only W staging
    __shared__ u16 xs_hi[4 * XS_STRIDE];
    __shared__ u16 xs_lo[4 * XS_STRIDE];
    __shared__ u16 hs_hi[4 * HS_STRIDE];
    __shared__ u16 hs_lo[4 * HS_STRIDE];

    const int tid  = threadIdx.x;
    const int wave = tid >> 6;
    const int lane = tid & 63;
    const int n    = lane & 15;
    const int quad = lane >> 4;
    const int g    = blockIdx.x & 15;
    const int cb   = blockIdx.x >> 4;
    const int jme  = cb * 64 + wave * 16 + n;   // my output column

    // ---- init: W column-slice -> split-bf16 register B-fragments ----
    // B-frag layout (16x16x32): n = lane&15, k = quad*8 + i
    // FULL unroll: all whi/wlo indices compile-time -> register allocation.
    short8 whi[32], wlo[32];
    #pragma unroll
    for (int ph = 0; ph < 8; ++ph) {            // 8 phases x 128 rows
        #pragma unroll
        for (int ii = 0; ii < 8; ++ii) {        // stage 128x64 fp32 tile
            int f4i = ii * 256 + tid;           // 2048 float4
            int row = f4i >> 4, c4 = (f4i & 15) * 4;
            *(float4*)(Wl + row * 68 + c4) =
                *(const float4*)(W + (size_t)(ph * 128 + row) * H_ + cb * 64 + c4);
        }
        __syncthreads();
        #pragma unroll
        for (int ckl = 0; ckl < 4; ++ckl) {     // K-chunks of 32 within phase
            short8 fh, fl;
            #pragma unroll
            for (int i = 0; i < 8; ++i) {
                float v = Wl[(ckl * 32 + quad * 8 + i) * 68 + wave * 16 + n];
                u16 h, l; split_bf(v, h, l);
                fh[i] = (short)h; fl[i] = (short)l;
            }
            whi[ph * 4 + ckl] = fh;
            wlo[ph * 4 + ckl] = fl;
        }
        __syncthreads();
    }

    // in_w fragments: B[k][col] = in_w[col][k] -> 8 consecutive fp32 per chunk
    short8 iwhi[8], iwlo[8];
    #pragma unroll
    for (int ck = 0; ck < 8; ++ck) {
        float4 a = *(const float4*)(in_w + (size_t)jme * I_ + ck * 32 + quad * 8);
        float4 b = *(const float4*)(in_w + (size_t)jme * I_ + ck * 32 + quad * 8 + 4);
        short8 fh, fl;
        float vv[8] = {a.x, a.y, a.z, a.w, b.x, b.y, b.z, b.w};
        #pragma unroll
        for (int i = 0; i < 8; ++i) {
            u16 h, l; split_bf(vv[i], h, l);
            fh[i] = (short)h; fl[i] = (short)l;
        }
        iwhi[ck] = fh; iwlo[ck] = fl;
    }

    // per-column params (alpha time-invariant)
    float tv = taus[jme];
    float sg = 1.0f / (1.0f + __expf(-tv));
    float al = 10.0f / (sg * 90.0f + 10.0f);   // DT / (sigmoid(taus)*range + min)
    float om = 1.0f - al;
    float bj = in_b[jme];
    float hm[4] = {0.f, 0.f, 0.f, 0.f};        // fp32 master h (quad-0 lanes)

    unsigned* myc = cnt + g * CNT_STRIDE;

    #pragma unroll 1
    for (int t = 0; t < T_; ++t) {
        // ---- off-critical-path: eps prefetch + x_t staging (split-bf16) ----
        float epr[4];
        if (quad == 0) {
            #pragma unroll
            for (int r = 0; r < 4; ++r)
                epr[r] = eps[((g * 4 + r) * T_ + t) * H_ + jme];
        }
        {
            int b = tid >> 6, c = (tid & 63) * 4;    // 256 float4 = [4][256]
            float4 xv = *(const float4*)(x + ((g * 4 + b) * T_ + t) * I_ + c);
            u64 hi64, lo64; split4(xv, hi64, lo64);
            *(u64*)(xs_hi + b * XS_STRIDE + c) = hi64;
            *(u64*)(xs_lo + b * XS_STRIDE + c) = lo64;
        }
        __syncthreads();                                        // S0: xs ready

        // ---- wait for h_t publication from all 16 peers of this group ----
        // No acquire fence: h is read below with agent-scope (sc0 sc1) loads
        // that bypass L1/L2, so there are no stale cached lines to kill.
        if (tid == 0 && t > 0) {
            unsigned tgt = 16u * (unsigned)t;
            while (__hip_atomic_load(myc, __ATOMIC_RELAXED, __HIP_MEMORY_SCOPE_AGENT) < tgt)
                __builtin_amdgcn_s_sleep(1);
        }
        __syncthreads();                                        // S1: h published

        // ---- issue coherent h_t loads (8 x dwordx2, device coherence point);
        //      their ~900cy latency hides under the x-projection MFMAs below ----
        u64 hv[8];
        {
            u64* src8 = (u64*)(hbf + (size_t)((t & 1) * 16 + g) * 4096);
            #pragma unroll
            for (int ii = 0; ii < 8; ++ii)
                hv[ii] = __hip_atomic_load(src8 + ii * 256 + tid,
                                           __ATOMIC_RELAXED, __HIP_MEMORY_SCOPE_AGENT);
        }

        // ---- x @ in_w^T while h loads are in flight (24 MFMAs) ----
        floatx4 acc[8];
        #pragma unroll
        for (int a8 = 0; a8 < 8; ++a8) { floatx4 z = {0.f,0.f,0.f,0.f}; acc[a8] = z; }
        {
            const u16* xh = xs_hi + (n & 3) * XS_STRIDE + quad * 8;
            const u16* xl = xs_lo + (n & 3) * XS_STRIDE + quad * 8;
            #pragma unroll
            for (int ck = 0; ck < 8; ++ck) {
                short8 ah  = *(const short8*)(xh + ck * 32);
                short8 al8 = *(const short8*)(xl + ck * 32);
                acc[ck] = MFMA16(ah, iwhi[ck], acc[ck], 0, 0, 0);
                acc[ck] = MFMA16(ah, iwlo[ck], acc[ck], 0, 0, 0);
                acc[ck] = MFMA16(al8, iwhi[ck], acc[ck], 0, 0, 0);
            }
        }

        // ---- consume h loads: split-bf16 -> LDS ----
        {
            #pragma unroll
            for (int ii = 0; ii < 8; ++ii) {
                int idx = ii * 256 + tid;              // 2048 u64 = [4][512]
                int b = idx >> 9, c = (idx & 511) * 2;
                float f0 = __uint_as_float((u32)hv[ii]);
                float f1 = __uint_as_float((u32)(hv[ii] >> 32));
                u16 h0, l0, h1, l1;
                split_bf(f0, h0, l0); split_bf(f1, h1, l1);
                *(u32*)(hs_hi + b * HS_STRIDE + c) = (u32)h0 | ((u32)h1 << 16);
                *(u32*)(hs_lo + b * HS_STRIDE + c) = (u32)l0 | ((u32)l1 << 16);
            }
        }
        __syncthreads();                                        // S2: hs ready

        // ---- h @ W: 32 K-chunks x 3 split terms = 96 MFMAs ----
        {
            const u16* hh = hs_hi + (n & 3) * HS_STRIDE + quad * 8;
            const u16* hl = hs_lo + (n & 3) * HS_STRIDE + quad * 8;
            #pragma unroll
            for (int ck = 0; ck < 32; ++ck) {
                short8 ah  = *(const short8*)(hh + ck * 32);
                short8 al8 = *(const short8*)(hl + ck * 32);
                acc[ck & 7] = MFMA16(ah, whi[ck], acc[ck & 7], 0, 0, 0);
                acc[ck & 7] = MFMA16(ah, wlo[ck], acc[ck & 7], 0, 0, 0);
                acc[ck & 7] = MFMA16(al8, whi[ck], acc[ck & 7], 0, 0, 0);
            }
        }

        // ---- epilogue: C/D row = quad*4+reg -> quad 0 holds batches 0..3 ----
        if (quad == 0) {
            float* dst = hbf + (size_t)(((t + 1) & 1) * 16 + g) * 4096;
            #pragma unroll
            for (int r = 0; r < 4; ++r) {
                float pre = acc[0][r] + acc[1][r] + acc[2][r] + acc[3][r]
                          + acc[4][r] + acc[5][r] + acc[6][r] + acc[7][r]
                          + bj + 0.1f * epr[r];
                float ex = __expf(2.0f * pre);                 // tanh = 1 - 2/(e^2x+1)
                float th = 1.0f - 2.0f / (ex + 1.0f);
                hm[r] = om * hm[r] + al * th;
                out[((g * 4 + r) * T_ + t) * H_ + jme] = hm[r];
                // publish via sc1 store (bypasses L2 -> visible at coherence point)
                __hip_atomic_store((u32*)(dst + r * H_ + jme), __float_as_uint(hm[r]),
                                   __ATOMIC_RELAXED, __HIP_MEMORY_SCOPE_AGENT);
            }
        }
        __syncthreads();   // S3: barrier drains every wave's vmcnt -> all sc1
                           // publish stores are ack'd at the coherence point
                           // before wave 0 issues the counter bump below.
        if (tid == 0)
            __hip_atomic_fetch_add(myc, 1u, __ATOMIC_RELAXED, __HIP_MEMORY_SCOPE_AGENT);
    }
}

extern "C" void kernel_launch(void* const* d_in, const int* in_sizes, int n_in,
                              void* d_out, int out_size, void* d_ws, size_t ws_size,
                              hipStream_t stream) {
    const float* x    = (const float*)d_in[0];
    const float* eps  = (const float*)d_in[1];
    const float* in_w = (const float*)d_in[2];
    const float* in_b = (const float*)d_in[3];
    const float* W    = (const float*)d_in[4];
    const float* taus = (const float*)d_in[5];
    float* out = (float*)d_out;

    unsigned* cnt = (unsigned*)d_ws;                   // 16 counters @ 256B stride
    float* hbf = (float*)((char*)d_ws + 4096);         // [parity][16 groups][4][1024] fp32

    // zero counters + parity-0 h (h0 = 0); parity-1 is fully written before read
    hipMemsetAsync(d_ws, 0, 4096 + 16 * 4096 * sizeof(float), stream);

    leaky_rnn<<<dim3(256), dim3(256), 0, stream>>>(x, eps, in_w, in_b, W, taus,
                                                   out, hbf, cnt);
}

// Round 3
// 2357.508 us; speedup vs baseline: 4.1796x; 1.0716x over previous
//
#include <hip/hip_runtime.h>

typedef short short8 __attribute__((ext_vector_type(8)));
typedef float floatx4 __attribute__((ext_vector_type(4)));
typedef unsigned short u16;
typedef unsigned u32;
typedef unsigned long long u64;

#define MFMA16 __builtin_amdgcn_mfma_f32_16x16x32_bf16

#define B_  64
#define T_  512
#define I_  256
#define H_  1024
#define XS_STRIDE 272    // u16; 544B = 8 banks mod 32 -> 2-way max on A-reads
#define HS_STRIDE 1040   // u16; 2080B = 8 banks mod 32

// round-to-nearest-even fp32 -> bf16 (as u16)
__device__ __forceinline__ u16 rne_bf(float f) {
    union { float f; u32 i; } v; v.f = f;
    return (u16)((v.i + 0x7fffu + ((v.i >> 16) & 1u)) >> 16);
}
// split fp32 into bf16 hi + bf16 lo (hi RNE, lo = RNE(f - hi)); |f-hi-lo| <= 2^-16 |f|
__device__ __forceinline__ void split_bf(float f, u16& hi, u16& lo) {
    u16 h = rne_bf(f);
    union { u32 i; float f; } hf; hf.i = ((u32)h) << 16;
    hi = h;
    lo = rne_bf(f - hf.f);
}
__device__ __forceinline__ void split4(float4 v, u64& hi64, u64& lo64) {
    u16 h0,l0,h1,l1,h2,l2,h3,l3;
    split_bf(v.x,h0,l0); split_bf(v.y,h1,l1);
    split_bf(v.z,h2,l2); split_bf(v.w,h3,l3);
    hi64 = (u64)h0 | ((u64)h1 << 16) | ((u64)h2 << 32) | ((u64)h3 << 48);
    lo64 = (u64)l0 | ((u64)l1 << 16) | ((u64)l2 << 32) | ((u64)l3 << 48);
}

// grid = 256 blocks: blockIdx = cb*16 + g
//   g  (0..15): batch group, batches 4g..4g+3  (stride-16 peers -> same XCD under %8)
//   cb (0..15): column block, cols 64cb..64cb+63
// block = 256 threads = 4 waves; wave w owns cols 64cb+16w .. +15
//
// h exchange is TAGGED-VALUE: each published element is a u64
//   (tag = step)<<48 | lo_bf16<<16 | hi_bf16
// written with one sc1 atomic store.  Consumers poll their own data words for
// the tag -- the poll load IS the data load.  This removes the counter
// fetch_add, the tid0-poll + its barrier, and the producer-side store-ack
// drain from the critical path (was ~3 serial MALL round-trips; now ~1).
// Slot parity (t&1) double-buffers; a slot is only overwritten (tag t+1)
// after every peer published tag t, which is strictly after their tag-(t-1)
// reads of that slot completed -> race-free.
__global__ __launch_bounds__(256, 1) void leaky_rnn(
    const float* __restrict__ x, const float* __restrict__ eps,
    const float* __restrict__ in_w, const float* __restrict__ in_b,
    const float* __restrict__ W, const float* __restrict__ taus,
    float* __restrict__ out, u64* __restrict__ hbf, unsigned* __restrict__ cnt)
{
    __shared__ float Wl[128 * 68];           // init-only W staging
    __shared__ u16 xs_hi[4 * XS_STRIDE];
    __shared__ u16 xs_lo[4 * XS_STRIDE];
    __shared__ u16 hs_hi[4 * HS_STRIDE];
    __shared__ u16 hs_lo[4 * HS_STRIDE];

    const int tid  = threadIdx.x;
    const int wave = tid >> 6;
    const int lane = tid & 63;
    const int n    = lane & 15;
    const int quad = lane >> 4;
    const int g    = blockIdx.x & 15;
    const int cb   = blockIdx.x >> 4;
    const int jme  = cb * 64 + wave * 16 + n;   // my output column

    // ---- init: W column-slice -> split-bf16 register B-fragments ----
    // B-frag layout (16x16x32): n = lane&15, k = quad*8 + i
    // FULL unroll: all whi/wlo indices compile-time -> register allocation
    // (runtime-indexed ext_vector arrays go to scratch: 17 GB/launch lesson).
    short8 whi[32], wlo[32];
    #pragma unroll
    for (int ph = 0; ph < 8; ++ph) {            // 8 phases x 128 rows
        #pragma unroll
        for (int ii = 0; ii < 8; ++ii) {        // stage 128x64 fp32 tile
            int f4i = ii * 256 + tid;           // 2048 float4
            int row = f4i >> 4, c4 = (f4i & 15) * 4;
            *(float4*)(Wl + row * 68 + c4) =
                *(const float4*)(W + (size_t)(ph * 128 + row) * H_ + cb * 64 + c4);
        }
        __syncthreads();
        #pragma unroll
        for (int ckl = 0; ckl < 4; ++ckl) {     // K-chunks of 32 within phase
            short8 fh, fl;
            #pragma unroll
            for (int i = 0; i < 8; ++i) {
                float v = Wl[(ckl * 32 + quad * 8 + i) * 68 + wave * 16 + n];
                u16 h, l; split_bf(v, h, l);
                fh[i] = (short)h; fl[i] = (short)l;
            }
            whi[ph * 4 + ckl] = fh;
            wlo[ph * 4 + ckl] = fl;
        }
        __syncthreads();
    }

    // in_w fragments: B[k][col] = in_w[col][k] -> 8 consecutive fp32 per chunk
    short8 iwhi[8], iwlo[8];
    #pragma unroll
    for (int ck = 0; ck < 8; ++ck) {
        float4 a = *(const float4*)(in_w + (size_t)jme * I_ + ck * 32 + quad * 8);
        float4 b = *(const float4*)(in_w + (size_t)jme * I_ + ck * 32 + quad * 8 + 4);
        short8 fh, fl;
        float vv[8] = {a.x, a.y, a.z, a.w, b.x, b.y, b.z, b.w};
        #pragma unroll
        for (int i = 0; i < 8; ++i) {
            u16 h, l; split_bf(vv[i], h, l);
            fh[i] = (short)h; fl[i] = (short)l;
        }
        iwhi[ck] = fh; iwlo[ck] = fl;
    }

    // per-column params (alpha time-invariant)
    float tv = taus[jme];
    float sg = 1.0f / (1.0f + __expf(-tv));
    float al = 10.0f / (sg * 90.0f + 10.0f);   // DT / (sigmoid(taus)*range + min)
    float om = 1.0f - al;
    float bj = in_b[jme];
    float hm[4] = {0.f, 0.f, 0.f, 0.f};        // fp32 master h (quad-0 lanes)

    // ---- prologue: prefetch x(0), eps(0) into registers ----
    float4 xv;
    float epr[4] = {0.f, 0.f, 0.f, 0.f};
    {
        int b = tid >> 6, c = (tid & 63) * 4;
        xv = *(const float4*)(x + ((size_t)(g * 4 + b) * T_ + 0) * I_ + c);
    }
    if (quad == 0) {
        #pragma unroll
        for (int r = 0; r < 4; ++r)
            epr[r] = eps[((size_t)(g * 4 + r) * T_ + 0) * H_ + jme];
    }

    #pragma unroll 1
    for (int t = 0; t < T_; ++t) {
        // ---- stage x_t (already in registers) -> split-bf16 LDS ----
        {
            int b = tid >> 6, c = (tid & 63) * 4;    // 256 float4 = [4][256]
            u64 hi64, lo64; split4(xv, hi64, lo64);
            *(u64*)(xs_hi + b * XS_STRIDE + c) = hi64;
            *(u64*)(xs_lo + b * XS_STRIDE + c) = lo64;
        }
        __syncthreads();                                        // S0: xs ready

        // ---- issue tagged h_t poll loads (16 u64/thread, one sweep) ----
        u64 hv[16];
        u64* src8 = hbf + ((size_t)(t & 1) * 16 + g) * 4096;
        #pragma unroll
        for (int ii = 0; ii < 16; ++ii)
            hv[ii] = __hip_atomic_load(src8 + ii * 256 + tid,
                                       __ATOMIC_RELAXED, __HIP_MEMORY_SCOPE_AGENT);

        // ---- x @ in_w^T while the sweep is in flight (24 MFMAs) ----
        // acc rotation (3ck+j)&7: any 8 consecutive MFMAs hit distinct accs.
        floatx4 acc[8];
        #pragma unroll
        for (int a8 = 0; a8 < 8; ++a8) { floatx4 z = {0.f,0.f,0.f,0.f}; acc[a8] = z; }
        {
            const u16* xh = xs_hi + (n & 3) * XS_STRIDE + quad * 8;
            const u16* xl = xs_lo + (n & 3) * XS_STRIDE + quad * 8;
            #pragma unroll
            for (int ck = 0; ck < 8; ++ck) {
                short8 ah  = *(const short8*)(xh + ck * 32);
                short8 al8 = *(const short8*)(xl + ck * 32);
                acc[(3*ck+0)&7] = MFMA16(ah,  iwhi[ck], acc[(3*ck+0)&7], 0, 0, 0);
                acc[(3*ck+1)&7] = MFMA16(ah,  iwlo[ck], acc[(3*ck+1)&7], 0, 0, 0);
                acc[(3*ck+2)&7] = MFMA16(al8, iwhi[ck], acc[(3*ck+2)&7], 0, 0, 0);
            }
        }

        // ---- verify tags, re-sweep pending ----
        {
            u32 pend = 0;
            #pragma unroll
            for (int ii = 0; ii < 16; ++ii)
                if ((u32)(hv[ii] >> 48) != (u32)t) pend |= (1u << ii);
            while (pend) {
                #pragma unroll
                for (int ii = 0; ii < 16; ++ii)
                    if (pend & (1u << ii))
                        hv[ii] = __hip_atomic_load(src8 + ii * 256 + tid,
                                                   __ATOMIC_RELAXED, __HIP_MEMORY_SCOPE_AGENT);
                #pragma unroll
                for (int ii = 0; ii < 16; ++ii)
                    if ((u32)(hv[ii] >> 48) == (u32)t) pend &= ~(1u << ii);
            }
        }

        // ---- unpack pre-split bf16 h -> LDS (no VALU split needed) ----
        #pragma unroll
        for (int ii = 0; ii < 16; ++ii) {
            int idx = ii * 256 + tid;              // 4096 = [4][1024]
            int b = idx >> 10, c = idx & 1023;
            hs_hi[b * HS_STRIDE + c] = (u16)hv[ii];
            hs_lo[b * HS_STRIDE + c] = (u16)(hv[ii] >> 16);
        }
        __syncthreads();                                        // S2: hs ready

        // ---- prefetch x/eps for t+1 (latency hides under hW MFMAs) ----
        float4 xvn;
        float eprn[4] = {0.f, 0.f, 0.f, 0.f};
        {
            int tn = (t < T_ - 1) ? t + 1 : t;
            int b = tid >> 6, c = (tid & 63) * 4;
            xvn = *(const float4*)(x + ((size_t)(g * 4 + b) * T_ + tn) * I_ + c);
            if (quad == 0) {
                #pragma unroll
                for (int r = 0; r < 4; ++r)
                    eprn[r] = eps[((size_t)(g * 4 + r) * T_ + tn) * H_ + jme];
            }
        }

        // ---- h @ W: 32 K-chunks x 3 split terms = 96 MFMAs ----
        {
            const u16* hh = hs_hi + (n & 3) * HS_STRIDE + quad * 8;
            const u16* hl = hs_lo + (n & 3) * HS_STRIDE + quad * 8;
            #pragma unroll
            for (int ck = 0; ck < 32; ++ck) {
                short8 ah  = *(const short8*)(hh + ck * 32);
                short8 al8 = *(const short8*)(hl + ck * 32);
                acc[(3*ck+0)&7] = MFMA16(ah,  whi[ck], acc[(3*ck+0)&7], 0, 0, 0);
                acc[(3*ck+1)&7] = MFMA16(ah,  wlo[ck], acc[(3*ck+1)&7], 0, 0, 0);
                acc[(3*ck+2)&7] = MFMA16(al8, whi[ck], acc[(3*ck+2)&7], 0, 0, 0);
            }
        }

        // ---- epilogue: C/D row = quad*4+reg -> quad 0 holds batches 0..3 ----
        if (quad == 0) {
            u64* dst8 = hbf + ((size_t)((t + 1) & 1) * 16 + g) * 4096;
            #pragma unroll
            for (int r = 0; r < 4; ++r) {
                float pre = acc[0][r] + acc[1][r] + acc[2][r] + acc[3][r]
                          + acc[4][r] + acc[5][r] + acc[6][r] + acc[7][r]
                          + bj + 0.1f * epr[r];
                float ex = __expf(2.0f * pre);                 // tanh = 1 - 2/(e^2x+1)
                float th = 1.0f - 2.0f / (ex + 1.0f);
                hm[r] = om * hm[r] + al * th;
                out[((size_t)(g * 4 + r) * T_ + t) * H_ + jme] = hm[r];
                // publish tagged split-bf16 value; fire-and-forget sc1 store
                u16 ph, pl; split_bf(hm[r], ph, pl);
                u64 pk = (u64)ph | ((u64)pl << 16) | ((u64)(u32)(t + 1) << 48);
                __hip_atomic_store(dst8 + r * 1024 + jme, pk,
                                   __ATOMIC_RELAXED, __HIP_MEMORY_SCOPE_AGENT);
            }
        }

        // roll prefetched registers
        xv = xvn;
        #pragma unroll
        for (int r = 0; r < 4; ++r) epr[r] = eprn[r];
        // no end-of-step barrier needed: next write to xs happens after the
        // next S0-producing split4, and every wave passed S2 (xs reads done);
        // hs writes at t+1 happen after the t+1 poll, past S0(t+1).
    }
}

extern "C" void kernel_launch(void* const* d_in, const int* in_sizes, int n_in,
                              void* d_out, int out_size, void* d_ws, size_t ws_size,
                              hipStream_t stream) {
    const float* x    = (const float*)d_in[0];
    const float* eps  = (const float*)d_in[1];
    const float* in_w = (const float*)d_in[2];
    const float* in_b = (const float*)d_in[3];
    const float* W    = (const float*)d_in[4];
    const float* taus = (const float*)d_in[5];
    float* out = (float*)d_out;

    unsigned* cnt = (unsigned*)d_ws;                   // unused (kept for layout)
    u64* hbf = (u64*)((char*)d_ws + 4096);             // [parity][16 groups][4096] u64

    // zero BOTH parity slots: tag 0 == step 0 (h0 = 0); stale tags from a
    // previous dispatch must never alias a live step tag.
    hipMemsetAsync(d_ws, 0, 4096 + 2 * 16 * 4096 * sizeof(u64), stream);

    leaky_rnn<<<dim3(256), dim3(256), 0, stream>>>(x, eps, in_w, in_b, W, taus,
                                                   out, hbf, cnt);
}